// Round 1
// baseline (223.163 us; speedup 1.0000x reference)
//
#include <hip/hip_runtime.h>
#include <hip/hip_bf16.h>

#define ETA_MIN 2.302585092994046f  // log(10)
#define ETA_MAX 20.0f

// Elementwise: w_i = (loss_i > eta) ? 0 : 1 - loss_i/eta, eta = clamp(eta_value[0], ETA_MIN, ETA_MAX)
// Memory-bound: 256 MB total traffic, roofline ~41 us at 6.3 TB/s.
__global__ void Weightfun_78374563217418_kernel(const float4* __restrict__ loss,
                                                const float* __restrict__ eta_ptr,
                                                float4* __restrict__ out,
                                                int n4) {
    int i = blockIdx.x * blockDim.x + threadIdx.x;
    // scalar broadcast load; clamped per reference
    float eta = eta_ptr[0];
    eta = fminf(fmaxf(eta, ETA_MIN), ETA_MAX);
    float inv_eta = 1.0f / eta;  // one precise divide per thread, hoisted out of the vector lanes

    if (i < n4) {
        float4 l = loss[i];
        float4 w;
        w.x = (l.x > eta) ? 0.0f : fmaf(-l.x, inv_eta, 1.0f);
        w.y = (l.y > eta) ? 0.0f : fmaf(-l.y, inv_eta, 1.0f);
        w.z = (l.z > eta) ? 0.0f : fmaf(-l.z, inv_eta, 1.0f);
        w.w = (l.w > eta) ? 0.0f : fmaf(-l.w, inv_eta, 1.0f);
        out[i] = w;
    }
}

extern "C" void kernel_launch(void* const* d_in, const int* in_sizes, int n_in,
                              void* d_out, int out_size, void* d_ws, size_t ws_size,
                              hipStream_t stream) {
    const float4* loss   = (const float4*)d_in[0];
    const float*  eta    = (const float*)d_in[1];
    float4*       out    = (float4*)d_out;

    int n  = in_sizes[0];          // 33554432 = 2^25, divisible by 4
    int n4 = n / 4;                // 8388608
    int block = 256;
    int grid  = (n4 + block - 1) / block;  // 32768 — plenty to saturate 256 CUs

    Weightfun_78374563217418_kernel<<<grid, block, 0, stream>>>(loss, eta, out, n4);
}

// Round 3
// 216.224 us; speedup vs baseline: 1.0321x; 1.0321x over previous
//
#include <hip/hip_runtime.h>
#include <hip/hip_bf16.h>

#define ETA_MIN 2.302585092994046f  // log(10)
#define ETA_MAX 20.0f

// Native clang vector type — HIP's float4 is a struct and is rejected by
// __builtin_nontemporal_load/store; ext_vector_type(4) float is accepted.
typedef float v4f __attribute__((ext_vector_type(4)));

// Elementwise: w_i = (loss_i > eta) ? 0 : 1 - loss_i/eta, eta = clamp(eta_value[0], ETA_MIN, ETA_MAX)
// Memory-bound: 256 MB total traffic, roofline ~41 us at 6.3 TB/s achievable.
// Both streams are touched exactly once -> nontemporal loads/stores (nt flag)
// to avoid L2/LLC write-allocate + retention pollution on a pure stream.
__global__ void Weightfun_78374563217418_kernel(const v4f* __restrict__ loss,
                                                const float* __restrict__ eta_ptr,
                                                v4f* __restrict__ out,
                                                int n4) {
    int i = blockIdx.x * blockDim.x + threadIdx.x;
    // scalar broadcast load; clamped per reference
    float eta = eta_ptr[0];
    eta = fminf(fmaxf(eta, ETA_MIN), ETA_MAX);
    float inv_eta = 1.0f / eta;  // one precise divide per thread

    if (i < n4) {
        v4f l = __builtin_nontemporal_load(&loss[i]);
        v4f w;
        w.x = (l.x > eta) ? 0.0f : fmaf(-l.x, inv_eta, 1.0f);
        w.y = (l.y > eta) ? 0.0f : fmaf(-l.y, inv_eta, 1.0f);
        w.z = (l.z > eta) ? 0.0f : fmaf(-l.z, inv_eta, 1.0f);
        w.w = (l.w > eta) ? 0.0f : fmaf(-l.w, inv_eta, 1.0f);
        __builtin_nontemporal_store(w, &out[i]);
    }
}

extern "C" void kernel_launch(void* const* d_in, const int* in_sizes, int n_in,
                              void* d_out, int out_size, void* d_ws, size_t ws_size,
                              hipStream_t stream) {
    const v4f*   loss = (const v4f*)d_in[0];
    const float* eta  = (const float*)d_in[1];
    v4f*         out  = (v4f*)d_out;

    int n  = in_sizes[0];          // 33554432 = 2^25, divisible by 4
    int n4 = n / 4;                // 8388608
    int block = 256;
    int grid  = (n4 + block - 1) / block;  // 32768 — saturates 256 CUs

    Weightfun_78374563217418_kernel<<<grid, block, 0, stream>>>(loss, eta, out, n4);
}